// Round 7
// baseline (108.497 us; speedup 1.0000x reference)
//
#include <hip/hip_runtime.h>
#include <hip/hip_bf16.h>

// Problem constants
#define B_   2
#define CH   32      // C
#define S_   1024    // H*W
#define DM   64      // D_MODEL
#define NH   4       // N_HEADS
#define DH   16      // D_HEAD
#define COUT 64
#define L2E  1.44269504088896f

#if __has_builtin(__builtin_amdgcn_exp2f)
#define EXP2F(x) __builtin_amdgcn_exp2f(x)
#else
#define EXP2F(x) exp2f(x)
#endif

// ws layout (floats): [0 ..] w[n][h][s]  (64*4*1024 = 262144 floats, 1 MB)

// ---------------------------------------------------------------------------
// K1: 2048 blocks = (n 0..63) x (sch 0..31); 256 threads = (jh 2)x(h 4)x(sq 32).
// Per block: redundant prep of a[4]; gather channel row into LDS; min/max;
// each thread reduces HALF the j-range (512) for 1 s-value with 4-way split
// accumulators; halves combined via LDS; final w = num/den written directly.
__global__ __launch_bounds__(256) void k_attn(const float* __restrict__ x,
                                              const float* __restrict__ embed_w,
                                              const float* __restrict__ q_w,
                                              const float* __restrict__ k_w,
                                              float* __restrict__ w_out) {
    __shared__ __align__(16) float t[S_];
    __shared__ float sh[2 * 256];
    __shared__ float em_s[DM];
    __shared__ float a_s[NH];
    __shared__ float redmax[4], redmin[4];

    const int bid = blockIdx.x;
    const int tid = threadIdx.x;
    const int n = bid >> 5, sch = bid & 31;
    const int b = n >> 5, c = n & 31;

    // --- prep: a[h] = (qv.kv)|head_h / sqrt(DH), recomputed per block ---
    if (tid < DM) em_s[tid] = embed_w[tid];
    __syncthreads();
    {
        const int d = tid & 63, p = tid >> 6;
        float sq_ = 0.f, sk_ = 0.f;
        #pragma unroll
        for (int i = 0; i < 16; i++) {
            int e = p * 16 + i;
            float emv = em_s[e];
            sq_ = fmaf(q_w[d * DM + e], emv, sq_);
            sk_ = fmaf(k_w[d * DM + e], emv, sk_);
        }
        sh[tid] = sq_; sh[256 + tid] = sk_;
    }
    // --- stage channel row: t[s] = x[b, s, c], strided gather (L2/L3-resident) ---
    const float* xp = x + b * (S_ * CH) + c;
    float4 mv;
    {
        float v0 = xp[(tid * 4 + 0) * CH];
        float v1 = xp[(tid * 4 + 1) * CH];
        float v2 = xp[(tid * 4 + 2) * CH];
        float v3 = xp[(tid * 4 + 3) * CH];
        mv = make_float4(v0, v1, v2, v3);
        ((float4*)t)[tid] = mv;
    }
    __syncthreads();   // sh complete
    if (tid < NH) {
        float a = 0.f;
        #pragma unroll
        for (int i = 0; i < DH; i++) {
            int d = tid * DH + i;
            float qv = (sh[d] + sh[64 + d]) + (sh[128 + d] + sh[192 + d]);
            float kv = (sh[256 + d] + sh[320 + d]) + (sh[384 + d] + sh[448 + d]);
            a = fmaf(qv, kv, a);
        }
        a_s[tid] = a * 0.25f;   // 1/sqrt(16)
    }
    float lmax = fmaxf(fmaxf(mv.x, mv.y), fmaxf(mv.z, mv.w));
    float lmin = fminf(fminf(mv.x, mv.y), fminf(mv.z, mv.w));
    #pragma unroll
    for (int off = 32; off; off >>= 1) {
        lmax = fmaxf(lmax, __shfl_xor(lmax, off));
        lmin = fminf(lmin, __shfl_xor(lmin, off));
    }
    if ((tid & 63) == 0) { redmax[tid >> 6] = lmax; redmin[tid >> 6] = lmin; }
    __syncthreads();   // t, a_s, redmax/min all complete; sh reads done
    const float tmax = fmaxf(fmaxf(redmax[0], redmax[1]), fmaxf(redmax[2], redmax[3]));
    const float tmin = fminf(fminf(redmin[0], redmin[1]), fminf(redmin[2], redmin[3]));

    const int jh = tid >> 7;           // j-half
    const int h  = (tid >> 5) & 3;     // head
    const int sq = tid & 31;           // s within chunk
    const float a = a_s[h];
    const int s0 = sch * 32 + sq;
    const float ts0 = t[s0];

    const float cc  = ts0 * a;
    const float cc2 = cc * L2E;
    const float nm2 = -fmaxf(cc * tmax, cc * tmin) * L2E;  // exact logit max

    float an0 = 0.f, an1 = 0.f, an2 = 0.f, an3 = 0.f;
    float ad0 = 0.f, ad1 = 0.f, ad2 = 0.f, ad3 = 0.f;

    const float4* t4 = ((const float4*)t) + jh * 128;
    #pragma unroll 4
    for (int jq = 0; jq < 128; jq++) {
        float4 tj = t4[jq];                       // broadcast, conflict-free
        float e0 = EXP2F(fmaf(cc2, tj.x, nm2));
        float e1 = EXP2F(fmaf(cc2, tj.y, nm2));
        float e2 = EXP2F(fmaf(cc2, tj.z, nm2));
        float e3 = EXP2F(fmaf(cc2, tj.w, nm2));
        an0 = fmaf(e0, tj.x, an0); ad0 += e0;
        an1 = fmaf(e1, tj.y, an1); ad1 += e1;
        an2 = fmaf(e2, tj.z, an2); ad2 += e2;
        an3 = fmaf(e3, tj.w, an3); ad3 += e3;
    }
    const float an = (an0 + an1) + (an2 + an3);
    const float ad = (ad0 + ad1) + (ad2 + ad3);

    // combine the two j-halves via LDS (partner = tid ^ 128)
    sh[tid] = an; sh[256 + tid] = ad;
    __syncthreads();
    if (jh == 0) {
        float AN = an + sh[tid + 128];
        float AD = ad + sh[256 + tid + 128];
        w_out[(n * NH + h) * S_ + s0] = AN / AD;
    }
}

// ---------------------------------------------------------------------------
// K2: 128 blocks = (b 2) x (s-tile 64 of 16); 256 threads.
// Redundant prep of vv -> ov[64][4]; then W2[h][s] = sum_c merge[c]*w, and
// out[b,s,o] = sum_h ov[o][h]*W2[h][s].
__global__ __launch_bounds__(256) void k_fin(const float* __restrict__ w_arr,
                                             const float* __restrict__ embed_w,
                                             const float* __restrict__ v_w,
                                             const float* __restrict__ o_w,
                                             const float* __restrict__ merge_w,
                                             float* __restrict__ out) {
    __shared__ float em_s[DM];
    __shared__ float sh[256];
    __shared__ float vv[DM];
    __shared__ float ov_s[256];
    __shared__ float part[4][4][16];
    __shared__ float W2[4][16];
    __shared__ float msh[32];
    const int bid = blockIdx.x, tid = threadIdx.x;

    if (tid < DM) em_s[tid] = embed_w[tid];
    __syncthreads();
    {
        const int d = tid & 63, p = tid >> 6;
        float sv = 0.f;
        #pragma unroll
        for (int i = 0; i < 16; i++) {
            int e = p * 16 + i;
            sv = fmaf(v_w[d * DM + e], em_s[e], sv);
        }
        sh[tid] = sv;
    }
    __syncthreads();
    if (tid < DM) vv[tid] = (sh[tid] + sh[64 + tid]) + (sh[128 + tid] + sh[192 + tid]);
    if (tid < 32) msh[tid] = merge_w[tid];
    __syncthreads();
    {
        const int o = tid & 63, hh0 = tid >> 6;
        float s = 0.f;
        #pragma unroll
        for (int i = 0; i < DH; i++)
            s = fmaf(o_w[o * DM + hh0 * DH + i], vv[hh0 * DH + i], s);
        ov_s[o * NH + hh0] = s;
    }

    const int b  = bid >> 6;
    const int s0 = (bid & 63) * 16;
    const int sl = tid & 15, h = (tid >> 4) & 3, cg_ = tid >> 6;
    float acc = 0.f;
    #pragma unroll
    for (int k = 0; k < 8; k++) {
        int c = cg_ * 8 + k;
        acc = fmaf(msh[c], w_arr[((b * CH + c) * NH + h) * S_ + s0 + sl], acc);
    }
    part[cg_][h][sl] = acc;
    __syncthreads();   // ov_s and part complete
    if (tid < 64) {
        int hh = tid >> 4, ss = tid & 15;
        W2[hh][ss] = (part[0][hh][ss] + part[1][hh][ss]) +
                     (part[2][hh][ss] + part[3][hh][ss]);
    }
    __syncthreads();
    #pragma unroll
    for (int rep = 0; rep < 4; rep++) {
        int idx = rep * 256 + tid;
        int o2 = idx & 63, ss = idx >> 6;
        float r = 0.f;
        #pragma unroll
        for (int hh = 0; hh < NH; hh++)
            r = fmaf(ov_s[o2 * NH + hh], W2[hh][ss], r);
        out[(b * S_ + s0 + ss) * COUT + o2] = r;
    }
}

extern "C" void kernel_launch(void* const* d_in, const int* in_sizes, int n_in,
                              void* d_out, int out_size, void* d_ws, size_t ws_size,
                              hipStream_t stream) {
    const float* x       = (const float*)d_in[0];
    const float* embed_w = (const float*)d_in[1];
    const float* q_w     = (const float*)d_in[2];
    const float* k_w     = (const float*)d_in[3];
    const float* v_w     = (const float*)d_in[4];
    const float* o_w     = (const float*)d_in[5];
    const float* merge_w = (const float*)d_in[6];
    float* ws  = (float*)d_ws;
    float* out = (float*)d_out;

    k_attn<<<2048, 256, 0, stream>>>(x, embed_w, q_w, k_w, ws);
    k_fin<<<B_ * 64, 256, 0, stream>>>(ws, embed_w, v_w, o_w, merge_w, out);
}

// Round 10
// 92.173 us; speedup vs baseline: 1.1771x; 1.1771x over previous
//
#include <hip/hip_runtime.h>
#include <hip/hip_bf16.h>

// Problem constants
#define B_   2
#define CH   32      // C
#define S_   1024    // H*W
#define DM   64      // D_MODEL
#define NH   4       // N_HEADS
#define DH   16      // D_HEAD
#define COUT 64
#define NBIN 128
#define L2E  1.44269504088896f

#if __has_builtin(__builtin_amdgcn_exp2f)
#define EXP2F(x) __builtin_amdgcn_exp2f(x)
#else
#define EXP2F(x) exp2f(x)
#endif

// ws layout (floats):
//   [0 .. 262143]        w[n][h][s]   (64*4*1024, 1 MB)
//   [262144 .. 262399]   hdr[n][4]    = {b0, h_w, -, -}
//   [262400 .. 295167]   mom[n][128][4] = {count, S1, S2, S3}
#define WS_W   0
#define WS_HDR 262144
#define WS_M   262400

// ---------------------------------------------------------------------------
// K0: per-channel histogram moments. 64 blocks (one per n=(b,c)), 256 threads.
__global__ __launch_bounds__(256) void k_hist(const float* __restrict__ x,
                                              float* __restrict__ ws) {
    __shared__ float M[NBIN][4];
    __shared__ float redmax[4], redmin[4];
    const int bid = blockIdx.x, tid = threadIdx.x;
    const int b = bid >> 5, c = bid & 31;

    // zero moments
    #pragma unroll
    for (int i = tid; i < NBIN * 4; i += 256) ((float*)M)[i] = 0.f;

    // strided gather of this channel's 1024 values
    const float* xp = x + b * (S_ * CH) + c;
    float v0 = xp[(tid * 4 + 0) * CH];
    float v1 = xp[(tid * 4 + 1) * CH];
    float v2 = xp[(tid * 4 + 2) * CH];
    float v3 = xp[(tid * 4 + 3) * CH];

    float lmax = fmaxf(fmaxf(v0, v1), fmaxf(v2, v3));
    float lmin = fminf(fminf(v0, v1), fminf(v2, v3));
    #pragma unroll
    for (int off = 32; off; off >>= 1) {
        lmax = fmaxf(lmax, __shfl_xor(lmax, off));
        lmin = fminf(lmin, __shfl_xor(lmin, off));
    }
    if ((tid & 63) == 0) { redmax[tid >> 6] = lmax; redmin[tid >> 6] = lmin; }
    __syncthreads();
    const float tmax = fmaxf(fmaxf(redmax[0], redmax[1]), fmaxf(redmax[2], redmax[3]));
    const float tmin = fminf(fminf(redmin[0], redmin[1]), fminf(redmin[2], redmin[3]));
    const float h_w  = (tmax - tmin) * (1.f / NBIN);
    const float b0   = tmin + 0.5f * h_w;
    const float inv  = 1.f / h_w;

    const float vs[4] = {v0, v1, v2, v3};
    #pragma unroll
    for (int i = 0; i < 4; i++) {
        float t = vs[i];
        int k = (int)((t - tmin) * inv);
        k = k > (NBIN - 1) ? (NBIN - 1) : k;
        float d = t - fmaf((float)k, h_w, b0);
        atomicAdd(&M[k][0], 1.f);
        atomicAdd(&M[k][1], d);
        atomicAdd(&M[k][2], d * d);
        atomicAdd(&M[k][3], d * d * d);
    }
    __syncthreads();
    if (tid < NBIN)
        ((float4*)(ws + WS_M))[bid * NBIN + tid] = *(const float4*)&M[tid][0];
    if (tid == 0) {
        ws[WS_HDR + bid * 4 + 0] = b0;
        ws[WS_HDR + bid * 4 + 1] = h_w;
    }
}

// ---------------------------------------------------------------------------
// K1: 1024 blocks = (n 0..63) x (sg 0..15); 256 threads = (h 4) x (sl 64).
// Per thread: c = t_s * a_h; sweep 128 bins:
//   PF = n + C1*S1 + C2*S2 + C3*S3,  QG = S1 + C1*S2 + C2*S3  (= dPF/dc)
//   F += e*PF,  G += e*(b*PF + QG),  e = exp2(c*b*L2E - m2)
// w = G/F.
__global__ __launch_bounds__(256) void k_attn(const float* __restrict__ x,
                                              const float* __restrict__ embed_w,
                                              const float* __restrict__ q_w,
                                              const float* __restrict__ k_w,
                                              float* __restrict__ ws) {
    __shared__ __align__(16) float Msh[NBIN * 4];
    __shared__ float sh[2 * 256];
    __shared__ float em_s[DM];
    __shared__ float a_s[NH];

    const int bid = blockIdx.x, tid = threadIdx.x;
    const int n = bid >> 4, sg = bid & 15;
    const int b = n >> 5, c = n & 31;

    // --- redundant prep: a[h] = (qv.kv)|head_h / sqrt(DH) ---
    if (tid < DM) em_s[tid] = embed_w[tid];
    __syncthreads();
    {
        const int d = tid & 63, p = tid >> 6;
        float sq_ = 0.f, sk_ = 0.f;
        #pragma unroll
        for (int i = 0; i < 16; i++) {
            int e = p * 16 + i;
            float emv = em_s[e];
            sq_ = fmaf(q_w[d * DM + e], emv, sq_);
            sk_ = fmaf(k_w[d * DM + e], emv, sk_);
        }
        sh[tid] = sq_; sh[256 + tid] = sk_;
    }
    // stage this channel's moment table (2 KB)
    if (tid < NBIN)
        ((float4*)Msh)[tid] = ((const float4*)(ws + WS_M))[n * NBIN + tid];
    __syncthreads();
    if (tid < NH) {
        float a = 0.f;
        #pragma unroll
        for (int i = 0; i < DH; i++) {
            int d = tid * DH + i;
            float qv = (sh[d] + sh[64 + d]) + (sh[128 + d] + sh[192 + d]);
            float kv = (sh[256 + d] + sh[320 + d]) + (sh[384 + d] + sh[448 + d]);
            a = fmaf(qv, kv, a);
        }
        a_s[tid] = a * 0.25f;   // 1/sqrt(16)
    }
    __syncthreads();

    const float b0  = ws[WS_HDR + n * 4 + 0];
    const float h_w = ws[WS_HDR + n * 4 + 1];

    const int h  = tid >> 6;
    const int sl = tid & 63;
    const int s  = sg * 64 + sl;
    const float ts = x[(b * S_ + s) * CH + c];

    const float cc = ts * a_s[h];
    const float C1 = cc;
    const float C2 = cc * cc * 0.5f;
    const float C3 = C2 * cc * (1.f / 3.f);
    const float c2e = cc * L2E;
    const float bLast = fmaf((float)(NBIN - 1), h_w, b0);
    const float nm2 = -fmaxf(cc * b0, cc * bLast) * L2E;

    float F0 = 0.f, F1 = 0.f, G0 = 0.f, G1 = 0.f;
    #pragma unroll 4
    for (int k = 0; k < NBIN; k += 2) {
        float4 m0 = ((const float4*)Msh)[k];
        float4 m1 = ((const float4*)Msh)[k + 1];
        float bf0 = fmaf((float)k, h_w, b0);
        float bf1 = bf0 + h_w;
        float e0 = EXP2F(fmaf(c2e, bf0, nm2));
        float e1 = EXP2F(fmaf(c2e, bf1, nm2));
        float PF0 = fmaf(C3, m0.w, fmaf(C2, m0.z, fmaf(C1, m0.y, m0.x)));
        float PF1 = fmaf(C3, m1.w, fmaf(C2, m1.z, fmaf(C1, m1.y, m1.x)));
        float QG0 = fmaf(C2, m0.w, fmaf(C1, m0.z, m0.y));
        float QG1 = fmaf(C2, m1.w, fmaf(C1, m1.z, m1.y));
        F0 = fmaf(e0, PF0, F0);
        F1 = fmaf(e1, PF1, F1);
        G0 = fmaf(e0, fmaf(bf0, PF0, QG0), G0);
        G1 = fmaf(e1, fmaf(bf1, PF1, QG1), G1);
    }
    ws[WS_W + (n * NH + h) * S_ + s] = (G0 + G1) / (F0 + F1);
}

// ---------------------------------------------------------------------------
// K2: 128 blocks = (b 2) x (s-tile 64 of 16); 256 threads.
// Redundant prep of vv -> ov[64][4]; then W2[h][s] = sum_c merge[c]*w, and
// out[b,s,o] = sum_h ov[o][h]*W2[h][s].
__global__ __launch_bounds__(256) void k_fin(const float* __restrict__ w_arr,
                                             const float* __restrict__ embed_w,
                                             const float* __restrict__ v_w,
                                             const float* __restrict__ o_w,
                                             const float* __restrict__ merge_w,
                                             float* __restrict__ out) {
    __shared__ float em_s[DM];
    __shared__ float sh[256];
    __shared__ float vv[DM];
    __shared__ float ov_s[256];
    __shared__ float part[4][4][16];
    __shared__ float W2[4][16];
    __shared__ float msh[32];
    const int bid = blockIdx.x, tid = threadIdx.x;

    if (tid < DM) em_s[tid] = embed_w[tid];
    __syncthreads();
    {
        const int d = tid & 63, p = tid >> 6;
        float sv = 0.f;
        #pragma unroll
        for (int i = 0; i < 16; i++) {
            int e = p * 16 + i;
            sv = fmaf(v_w[d * DM + e], em_s[e], sv);
        }
        sh[tid] = sv;
    }
    __syncthreads();
    if (tid < DM) vv[tid] = (sh[tid] + sh[64 + tid]) + (sh[128 + tid] + sh[192 + tid]);
    if (tid < 32) msh[tid] = merge_w[tid];
    __syncthreads();
    {
        const int o = tid & 63, hh0 = tid >> 6;
        float s = 0.f;
        #pragma unroll
        for (int i = 0; i < DH; i++)
            s = fmaf(o_w[o * DM + hh0 * DH + i], vv[hh0 * DH + i], s);
        ov_s[o * NH + hh0] = s;
    }

    const int b  = bid >> 6;
    const int s0 = (bid & 63) * 16;
    const int sl = tid & 15, h = (tid >> 4) & 3, cg_ = tid >> 6;
    float acc = 0.f;
    #pragma unroll
    for (int k = 0; k < 8; k++) {
        int c = cg_ * 8 + k;
        acc = fmaf(msh[c], w_arr[((b * CH + c) * NH + h) * S_ + s0 + sl], acc);
    }
    part[cg_][h][sl] = acc;
    __syncthreads();   // ov_s and part complete
    if (tid < 64) {
        int hh = tid >> 4, ss = tid & 15;
        W2[hh][ss] = (part[0][hh][ss] + part[1][hh][ss]) +
                     (part[2][hh][ss] + part[3][hh][ss]);
    }
    __syncthreads();
    #pragma unroll
    for (int rep = 0; rep < 4; rep++) {
        int idx = rep * 256 + tid;
        int o2 = idx & 63, ss = idx >> 6;
        float r = 0.f;
        #pragma unroll
        for (int hh = 0; hh < NH; hh++)
            r = fmaf(ov_s[o2 * NH + hh], W2[hh][ss], r);
        out[(b * S_ + s0 + ss) * COUT + o2] = r;
    }
}

extern "C" void kernel_launch(void* const* d_in, const int* in_sizes, int n_in,
                              void* d_out, int out_size, void* d_ws, size_t ws_size,
                              hipStream_t stream) {
    const float* x       = (const float*)d_in[0];
    const float* embed_w = (const float*)d_in[1];
    const float* q_w     = (const float*)d_in[2];
    const float* k_w     = (const float*)d_in[3];
    const float* v_w     = (const float*)d_in[4];
    const float* o_w     = (const float*)d_in[5];
    const float* merge_w = (const float*)d_in[6];
    float* ws  = (float*)d_ws;
    float* out = (float*)d_out;

    k_hist<<<64, 256, 0, stream>>>(x, ws);
    k_attn<<<1024, 256, 0, stream>>>(x, embed_w, q_w, k_w, ws);
    k_fin<<<B_ * 64, 256, 0, stream>>>(ws, embed_w, v_w, o_w, merge_w, out);
}

// Round 11
// 89.421 us; speedup vs baseline: 1.2133x; 1.0308x over previous
//
#include <hip/hip_runtime.h>
#include <hip/hip_bf16.h>

// Problem constants
#define B_   2
#define CH   32      // C
#define S_   1024    // H*W
#define DM   64      // D_MODEL
#define NH   4       // N_HEADS
#define DH   16      // D_HEAD
#define COUT 64
#define NBIN 128
#define L2E  1.44269504088896f

#if __has_builtin(__builtin_amdgcn_exp2f)
#define EXP2F(x) __builtin_amdgcn_exp2f(x)
#else
#define EXP2F(x) exp2f(x)
#endif

// ws layout (floats):
//   [0 .. 262143]        w[n][h][s]   (64*4*1024, 1 MB)
//   [262144 .. 262399]   hdr[n][4]    = {b0, h_w, -, -}
//   [262400 .. 295167]   mom[n][128][4] = {count, S1, S2, S3}
#define WS_W   0
#define WS_HDR 262144
#define WS_M   262400

// ---------------------------------------------------------------------------
// K0: per-channel histogram moments. 64 blocks (one per n=(b,c)), 256 threads.
__global__ __launch_bounds__(256) void k_hist(const float* __restrict__ x,
                                              float* __restrict__ ws) {
    __shared__ float M[NBIN][4];
    __shared__ float redmax[4], redmin[4];
    const int bid = blockIdx.x, tid = threadIdx.x;
    const int b = bid >> 5, c = bid & 31;

    // zero moments
    #pragma unroll
    for (int i = tid; i < NBIN * 4; i += 256) ((float*)M)[i] = 0.f;

    // strided gather of this channel's 1024 values
    const float* xp = x + b * (S_ * CH) + c;
    float v0 = xp[(tid * 4 + 0) * CH];
    float v1 = xp[(tid * 4 + 1) * CH];
    float v2 = xp[(tid * 4 + 2) * CH];
    float v3 = xp[(tid * 4 + 3) * CH];

    float lmax = fmaxf(fmaxf(v0, v1), fmaxf(v2, v3));
    float lmin = fminf(fminf(v0, v1), fminf(v2, v3));
    #pragma unroll
    for (int off = 32; off; off >>= 1) {
        lmax = fmaxf(lmax, __shfl_xor(lmax, off));
        lmin = fminf(lmin, __shfl_xor(lmin, off));
    }
    if ((tid & 63) == 0) { redmax[tid >> 6] = lmax; redmin[tid >> 6] = lmin; }
    __syncthreads();
    const float tmax = fmaxf(fmaxf(redmax[0], redmax[1]), fmaxf(redmax[2], redmax[3]));
    const float tmin = fminf(fminf(redmin[0], redmin[1]), fminf(redmin[2], redmin[3]));
    const float h_w  = (tmax - tmin) * (1.f / NBIN);
    const float b0   = tmin + 0.5f * h_w;
    const float inv  = 1.f / h_w;

    const float vs[4] = {v0, v1, v2, v3};
    #pragma unroll
    for (int i = 0; i < 4; i++) {
        float t = vs[i];
        int k = (int)((t - tmin) * inv);
        k = k > (NBIN - 1) ? (NBIN - 1) : k;
        float d = t - fmaf((float)k, h_w, b0);
        atomicAdd(&M[k][0], 1.f);
        atomicAdd(&M[k][1], d);
        atomicAdd(&M[k][2], d * d);
        atomicAdd(&M[k][3], d * d * d);
    }
    __syncthreads();
    if (tid < NBIN)
        ((float4*)(ws + WS_M))[bid * NBIN + tid] = *(const float4*)&M[tid][0];
    if (tid == 0) {
        ws[WS_HDR + bid * 4 + 0] = b0;
        ws[WS_HDR + bid * 4 + 1] = h_w;
    }
}

// ---------------------------------------------------------------------------
// K1: 1024 blocks = (n 0..63) x (sg 0..15); 256 threads = (h 4) x (sl 64).
// Per thread: cc = t_s * a_h; sweep 128 bins in 4 chunks of 32.
// Geometric-ladder trick: within a chunk, e_{k+4} = e_k * r4 (r4 = exp2(cc*4h))
// so only 4 anchor exps per chunk (16 total vs 128). Anchor refresh every 32
// bins stops underflow propagation. Per bin:
//   PF = n + C1*S1 + C2*S2 + C3*S3,  QG = S1 + C1*S2 + C2*S3  (= dPF/dc)
//   F += e*PF,  G += e*(b*PF + QG)
// w = G/F.
__global__ __launch_bounds__(256) void k_attn(const float* __restrict__ x,
                                              const float* __restrict__ embed_w,
                                              const float* __restrict__ q_w,
                                              const float* __restrict__ k_w,
                                              float* __restrict__ ws) {
    __shared__ __align__(16) float Msh[NBIN * 4];
    __shared__ float sh[2 * 256];
    __shared__ float em_s[DM];
    __shared__ float a_s[NH];

    const int bid = blockIdx.x, tid = threadIdx.x;
    const int n = bid >> 4, sg = bid & 15;
    const int b = n >> 5, c = n & 31;

    // --- redundant prep: a[h] = (qv.kv)|head_h / sqrt(DH) ---
    if (tid < DM) em_s[tid] = embed_w[tid];
    __syncthreads();
    {
        const int d = tid & 63, p = tid >> 6;
        float sq_ = 0.f, sk_ = 0.f;
        #pragma unroll
        for (int i = 0; i < 16; i++) {
            int e = p * 16 + i;
            float emv = em_s[e];
            sq_ = fmaf(q_w[d * DM + e], emv, sq_);
            sk_ = fmaf(k_w[d * DM + e], emv, sk_);
        }
        sh[tid] = sq_; sh[256 + tid] = sk_;
    }
    // stage this channel's moment table (2 KB)
    if (tid < NBIN)
        ((float4*)Msh)[tid] = ((const float4*)(ws + WS_M))[n * NBIN + tid];
    __syncthreads();
    if (tid < NH) {
        float a = 0.f;
        #pragma unroll
        for (int i = 0; i < DH; i++) {
            int d = tid * DH + i;
            float qv = (sh[d] + sh[64 + d]) + (sh[128 + d] + sh[192 + d]);
            float kv = (sh[256 + d] + sh[320 + d]) + (sh[384 + d] + sh[448 + d]);
            a = fmaf(qv, kv, a);
        }
        a_s[tid] = a * 0.25f;   // 1/sqrt(16)
    }
    __syncthreads();

    const float b0  = ws[WS_HDR + n * 4 + 0];
    const float h_w = ws[WS_HDR + n * 4 + 1];

    const int h  = tid >> 6;
    const int sl = tid & 63;
    const int s  = sg * 64 + sl;
    const float ts = x[(b * S_ + s) * CH + c];

    const float cc = ts * a_s[h];
    const float C1 = cc;
    const float C2 = cc * cc * 0.5f;
    const float C3 = C2 * cc * (1.f / 3.f);
    const float c2e = cc * L2E;
    const float bLast = fmaf((float)(NBIN - 1), h_w, b0);
    const float nm2 = -fmaxf(cc * b0, cc * bLast) * L2E;

    const float r4 = EXP2F(c2e * (4.f * h_w));   // e^{cc*4h}, bounded (max-sub)

    float F0 = 0.f, F1 = 0.f, F2 = 0.f, F3 = 0.f;
    float G0 = 0.f, G1 = 0.f, G2 = 0.f, G3 = 0.f;

    #pragma unroll
    for (int chnk = 0; chnk < 4; chnk++) {
        const float bfb = fmaf((float)(chnk * 32), h_w, b0);
        // 4 anchor exps per chunk (underflow containment)
        float E0 = EXP2F(fmaf(c2e, bfb,             nm2));
        float E1 = EXP2F(fmaf(c2e, bfb + h_w,       nm2));
        float E2 = EXP2F(fmaf(c2e, bfb + 2.f * h_w, nm2));
        float E3 = EXP2F(fmaf(c2e, bfb + 3.f * h_w, nm2));
        #pragma unroll
        for (int t = 0; t < 8; t++) {
            const int kb = chnk * 32 + t * 4;
            float4 m0 = ((const float4*)Msh)[kb + 0];
            float4 m1 = ((const float4*)Msh)[kb + 1];
            float4 m2 = ((const float4*)Msh)[kb + 2];
            float4 m3 = ((const float4*)Msh)[kb + 3];
            const float bf0 = fmaf((float)(t * 4), h_w, bfb);
            const float bf1 = bf0 + h_w;
            const float bf2 = bf0 + 2.f * h_w;
            const float bf3 = bf0 + 3.f * h_w;
            float PF0 = fmaf(C3, m0.w, fmaf(C2, m0.z, fmaf(C1, m0.y, m0.x)));
            float PF1 = fmaf(C3, m1.w, fmaf(C2, m1.z, fmaf(C1, m1.y, m1.x)));
            float PF2 = fmaf(C3, m2.w, fmaf(C2, m2.z, fmaf(C1, m2.y, m2.x)));
            float PF3 = fmaf(C3, m3.w, fmaf(C2, m3.z, fmaf(C1, m3.y, m3.x)));
            float QG0 = fmaf(C2, m0.w, fmaf(C1, m0.z, m0.y));
            float QG1 = fmaf(C2, m1.w, fmaf(C1, m1.z, m1.y));
            float QG2 = fmaf(C2, m2.w, fmaf(C1, m2.z, m2.y));
            float QG3 = fmaf(C2, m3.w, fmaf(C1, m3.z, m3.y));
            F0 = fmaf(E0, PF0, F0);
            F1 = fmaf(E1, PF1, F1);
            F2 = fmaf(E2, PF2, F2);
            F3 = fmaf(E3, PF3, F3);
            G0 = fmaf(E0, fmaf(bf0, PF0, QG0), G0);
            G1 = fmaf(E1, fmaf(bf1, PF1, QG1), G1);
            G2 = fmaf(E2, fmaf(bf2, PF2, QG2), G2);
            G3 = fmaf(E3, fmaf(bf3, PF3, QG3), G3);
            E0 *= r4; E1 *= r4; E2 *= r4; E3 *= r4;
        }
    }
    const float F = (F0 + F1) + (F2 + F3);
    const float G = (G0 + G1) + (G2 + G3);
    ws[WS_W + (n * NH + h) * S_ + s] = G / F;
}

// ---------------------------------------------------------------------------
// K2: 128 blocks = (b 2) x (s-tile 64 of 16); 256 threads.
// Redundant prep of vv -> ov[64][4]; then W2[h][s] = sum_c merge[c]*w, and
// out[b,s,o] = sum_h ov[o][h]*W2[h][s].
__global__ __launch_bounds__(256) void k_fin(const float* __restrict__ w_arr,
                                             const float* __restrict__ embed_w,
                                             const float* __restrict__ v_w,
                                             const float* __restrict__ o_w,
                                             const float* __restrict__ merge_w,
                                             float* __restrict__ out) {
    __shared__ float em_s[DM];
    __shared__ float sh[256];
    __shared__ float vv[DM];
    __shared__ float ov_s[256];
    __shared__ float part[4][4][16];
    __shared__ float W2[4][16];
    __shared__ float msh[32];
    const int bid = blockIdx.x, tid = threadIdx.x;

    if (tid < DM) em_s[tid] = embed_w[tid];
    __syncthreads();
    {
        const int d = tid & 63, p = tid >> 6;
        float sv = 0.f;
        #pragma unroll
        for (int i = 0; i < 16; i++) {
            int e = p * 16 + i;
            sv = fmaf(v_w[d * DM + e], em_s[e], sv);
        }
        sh[tid] = sv;
    }
    __syncthreads();
    if (tid < DM) vv[tid] = (sh[tid] + sh[64 + tid]) + (sh[128 + tid] + sh[192 + tid]);
    if (tid < 32) msh[tid] = merge_w[tid];
    __syncthreads();
    {
        const int o = tid & 63, hh0 = tid >> 6;
        float s = 0.f;
        #pragma unroll
        for (int i = 0; i < DH; i++)
            s = fmaf(o_w[o * DM + hh0 * DH + i], vv[hh0 * DH + i], s);
        ov_s[o * NH + hh0] = s;
    }

    const int b  = bid >> 6;
    const int s0 = (bid & 63) * 16;
    const int sl = tid & 15, h = (tid >> 4) & 3, cg_ = tid >> 6;
    float acc = 0.f;
    #pragma unroll
    for (int k = 0; k < 8; k++) {
        int c = cg_ * 8 + k;
        acc = fmaf(msh[c], w_arr[((b * CH + c) * NH + h) * S_ + s0 + sl], acc);
    }
    part[cg_][h][sl] = acc;
    __syncthreads();   // ov_s and part complete
    if (tid < 64) {
        int hh = tid >> 4, ss = tid & 15;
        W2[hh][ss] = (part[0][hh][ss] + part[1][hh][ss]) +
                     (part[2][hh][ss] + part[3][hh][ss]);
    }
    __syncthreads();
    #pragma unroll
    for (int rep = 0; rep < 4; rep++) {
        int idx = rep * 256 + tid;
        int o2 = idx & 63, ss = idx >> 6;
        float r = 0.f;
        #pragma unroll
        for (int hh = 0; hh < NH; hh++)
            r = fmaf(ov_s[o2 * NH + hh], W2[hh][ss], r);
        out[(b * S_ + s0 + ss) * COUT + o2] = r;
    }
}

extern "C" void kernel_launch(void* const* d_in, const int* in_sizes, int n_in,
                              void* d_out, int out_size, void* d_ws, size_t ws_size,
                              hipStream_t stream) {
    const float* x       = (const float*)d_in[0];
    const float* embed_w = (const float*)d_in[1];
    const float* q_w     = (const float*)d_in[2];
    const float* k_w     = (const float*)d_in[3];
    const float* v_w     = (const float*)d_in[4];
    const float* o_w     = (const float*)d_in[5];
    const float* merge_w = (const float*)d_in[6];
    float* ws  = (float*)d_ws;
    float* out = (float*)d_out;

    k_hist<<<64, 256, 0, stream>>>(x, ws);
    k_attn<<<1024, 256, 0, stream>>>(x, embed_w, q_w, k_w, ws);
    k_fin<<<B_ * 64, 256, 0, stream>>>(ws, embed_w, v_w, o_w, merge_w, out);
}

// Round 12
// 81.329 us; speedup vs baseline: 1.3341x; 1.0995x over previous
//
#include <hip/hip_runtime.h>
#include <hip/hip_bf16.h>

// Problem constants
#define B_   2
#define CH   32      // C
#define S_   1024    // H*W
#define DM   64      // D_MODEL
#define NH   4       // N_HEADS
#define DH   16      // D_HEAD
#define COUT 64
#define NBIN 128
#define NNODE 256
#define L2E  1.44269504088896f

#if __has_builtin(__builtin_amdgcn_exp2f)
#define EXP2F(x) __builtin_amdgcn_exp2f(x)
#else
#define EXP2F(x) exp2f(x)
#endif

// ws layout (floats):
//   [0 .. 255]       hdr[n][4] = {tmin, inv_u = 255/range, -, -}
//   [512 .. 66047]   T[n][h][256]  tables (64*4*256 = 65536 floats)
#define WS_HDR 0
#define WS_T   512

// ---------------------------------------------------------------------------
// K1: one block per (n,h): 256 blocks x 256 threads.
// Phase 1: redundant prep a_h; gather channel row; min/max; histogram moments
//          (count,S1,S2,S3 per bin) in LDS.
// Phase 2: each thread = one node tau_i on [tmin,tmax]; evaluates
//          Phi(tau_i) = G/F via the 128-bin ladder sweep; writes T[n][h][i].
__global__ __launch_bounds__(256) void k_tab(const float* __restrict__ x,
                                             const float* __restrict__ embed_w,
                                             const float* __restrict__ q_w,
                                             const float* __restrict__ k_w,
                                             float* __restrict__ ws) {
    __shared__ __align__(16) float M[NBIN][4];
    __shared__ float sh[2 * 256];
    __shared__ float em_s[DM];
    __shared__ float a_s[NH];
    __shared__ float redmax[4], redmin[4];

    const int bid = blockIdx.x, tid = threadIdx.x;
    const int n = bid >> 2, h = bid & 3;
    const int b = n >> 5, c = n & 31;

    // zero moments + load embed
    #pragma unroll
    for (int i = tid; i < NBIN * 4; i += 256) ((float*)M)[i] = 0.f;
    if (tid < DM) em_s[tid] = embed_w[tid];
    __syncthreads();

    // qv/kv partial sums (4-way split over e)
    {
        const int d = tid & 63, p = tid >> 6;
        float sq_ = 0.f, sk_ = 0.f;
        #pragma unroll
        for (int i = 0; i < 16; i++) {
            int e = p * 16 + i;
            float emv = em_s[e];
            sq_ = fmaf(q_w[d * DM + e], emv, sq_);
            sk_ = fmaf(k_w[d * DM + e], emv, sk_);
        }
        sh[tid] = sq_; sh[256 + tid] = sk_;
    }
    // gather this channel's 1024 values (strided, L2/L3-resident)
    const float* xp = x + b * (S_ * CH) + c;
    float v0 = xp[(tid * 4 + 0) * CH];
    float v1 = xp[(tid * 4 + 1) * CH];
    float v2 = xp[(tid * 4 + 2) * CH];
    float v3 = xp[(tid * 4 + 3) * CH];
    float lmax = fmaxf(fmaxf(v0, v1), fmaxf(v2, v3));
    float lmin = fminf(fminf(v0, v1), fminf(v2, v3));
    #pragma unroll
    for (int off = 32; off; off >>= 1) {
        lmax = fmaxf(lmax, __shfl_xor(lmax, off));
        lmin = fminf(lmin, __shfl_xor(lmin, off));
    }
    if ((tid & 63) == 0) { redmax[tid >> 6] = lmax; redmin[tid >> 6] = lmin; }
    __syncthreads();   // sh, red complete

    if (tid < NH) {
        float a = 0.f;
        #pragma unroll
        for (int i = 0; i < DH; i++) {
            int d = tid * DH + i;
            float qv = (sh[d] + sh[64 + d]) + (sh[128 + d] + sh[192 + d]);
            float kv = (sh[256 + d] + sh[320 + d]) + (sh[384 + d] + sh[448 + d]);
            a = fmaf(qv, kv, a);
        }
        a_s[tid] = a * 0.25f;   // 1/sqrt(16)
    }
    const float tmax = fmaxf(fmaxf(redmax[0], redmax[1]), fmaxf(redmax[2], redmax[3]));
    const float tmin = fminf(fminf(redmin[0], redmin[1]), fminf(redmin[2], redmin[3]));
    const float h_w  = (tmax - tmin) * (1.f / NBIN);
    const float b0   = tmin + 0.5f * h_w;
    const float binv = 1.f / h_w;

    // histogram moments (LDS atomics)
    const float vs[4] = {v0, v1, v2, v3};
    #pragma unroll
    for (int i = 0; i < 4; i++) {
        float t = vs[i];
        int k = (int)((t - tmin) * binv);
        k = k > (NBIN - 1) ? (NBIN - 1) : k;
        float d = t - fmaf((float)k, h_w, b0);
        atomicAdd(&M[k][0], 1.f);
        atomicAdd(&M[k][1], d);
        atomicAdd(&M[k][2], d * d);
        atomicAdd(&M[k][3], d * d * d);
    }
    __syncthreads();   // M, a_s complete

    // ---- node sweep: tau = tmin + tid * (range/255) ----
    const float dtau = (tmax - tmin) * (1.f / (NNODE - 1));
    const float tau  = fmaf((float)tid, dtau, tmin);
    const float cc   = tau * a_s[h];
    const float C1 = cc;
    const float C2 = cc * cc * 0.5f;
    const float C3 = C2 * cc * (1.f / 3.f);
    const float c2e = cc * L2E;
    const float bLast = fmaf((float)(NBIN - 1), h_w, b0);
    const float nm2 = -fmaxf(cc * b0, cc * bLast) * L2E;
    const float r4 = EXP2F(c2e * (4.f * h_w));

    float F0 = 0.f, F1 = 0.f, F2 = 0.f, F3 = 0.f;
    float G0 = 0.f, G1 = 0.f, G2 = 0.f, G3 = 0.f;
    #pragma unroll
    for (int chnk = 0; chnk < 4; chnk++) {
        const float bfb = fmaf((float)(chnk * 32), h_w, b0);
        float E0 = EXP2F(fmaf(c2e, bfb,             nm2));
        float E1 = EXP2F(fmaf(c2e, bfb + h_w,       nm2));
        float E2 = EXP2F(fmaf(c2e, bfb + 2.f * h_w, nm2));
        float E3 = EXP2F(fmaf(c2e, bfb + 3.f * h_w, nm2));
        #pragma unroll
        for (int t = 0; t < 8; t++) {
            const int kb = chnk * 32 + t * 4;
            float4 m0 = *(const float4*)&M[kb + 0][0];
            float4 m1 = *(const float4*)&M[kb + 1][0];
            float4 m2 = *(const float4*)&M[kb + 2][0];
            float4 m3 = *(const float4*)&M[kb + 3][0];
            const float bf0 = fmaf((float)(t * 4), h_w, bfb);
            const float bf1 = bf0 + h_w;
            const float bf2 = bf0 + 2.f * h_w;
            const float bf3 = bf0 + 3.f * h_w;
            float PF0 = fmaf(C3, m0.w, fmaf(C2, m0.z, fmaf(C1, m0.y, m0.x)));
            float PF1 = fmaf(C3, m1.w, fmaf(C2, m1.z, fmaf(C1, m1.y, m1.x)));
            float PF2 = fmaf(C3, m2.w, fmaf(C2, m2.z, fmaf(C1, m2.y, m2.x)));
            float PF3 = fmaf(C3, m3.w, fmaf(C2, m3.z, fmaf(C1, m3.y, m3.x)));
            float QG0 = fmaf(C2, m0.w, fmaf(C1, m0.z, m0.y));
            float QG1 = fmaf(C2, m1.w, fmaf(C1, m1.z, m1.y));
            float QG2 = fmaf(C2, m2.w, fmaf(C1, m2.z, m2.y));
            float QG3 = fmaf(C2, m3.w, fmaf(C1, m3.z, m3.y));
            F0 = fmaf(E0, PF0, F0);
            F1 = fmaf(E1, PF1, F1);
            F2 = fmaf(E2, PF2, F2);
            F3 = fmaf(E3, PF3, F3);
            G0 = fmaf(E0, fmaf(bf0, PF0, QG0), G0);
            G1 = fmaf(E1, fmaf(bf1, PF1, QG1), G1);
            G2 = fmaf(E2, fmaf(bf2, PF2, QG2), G2);
            G3 = fmaf(E3, fmaf(bf3, PF3, QG3), G3);
            E0 *= r4; E1 *= r4; E2 *= r4; E3 *= r4;
        }
    }
    const float F = (F0 + F1) + (F2 + F3);
    const float G = (G0 + G1) + (G2 + G3);
    ws[WS_T + (n * NH + h) * NNODE + tid] = G / F;
    if (tid == 0) {
        ws[WS_HDR + n * 4 + 0] = tmin;
        ws[WS_HDR + n * 4 + 1] = (float)(NNODE - 1) / (tmax - tmin);
    }
}

// ---------------------------------------------------------------------------
// K2: 128 blocks = (b 2) x (s-tile 64 of 16); 256 threads.
// Redundant prep of vv -> ov[64][4]; per output: table-interp eval of
// w = Phi_{n,h}(x[b,s,c]); W2[h][s] = sum_c merge[c]*w; out = ov @ W2.
__global__ __launch_bounds__(256) void k_fin(const float* __restrict__ ws,
                                             const float* __restrict__ x,
                                             const float* __restrict__ embed_w,
                                             const float* __restrict__ v_w,
                                             const float* __restrict__ o_w,
                                             const float* __restrict__ merge_w,
                                             float* __restrict__ out) {
    __shared__ float em_s[DM];
    __shared__ float sh[256];
    __shared__ float vv[DM];
    __shared__ float ov_s[256];
    __shared__ float part[4][4][16];
    __shared__ float W2[4][16];
    __shared__ float msh[32];
    __shared__ float hdr_s[CH][2];
    const int bid = blockIdx.x, tid = threadIdx.x;
    const int b  = bid >> 6;
    const int s0 = (bid & 63) * 16;

    if (tid < DM) em_s[tid] = embed_w[tid];
    if (tid >= 64 && tid < 128) {
        int c = (tid - 64) >> 1, j = tid & 1;
        hdr_s[c][j] = ws[WS_HDR + (b * CH + c) * 4 + j];
    }
    if (tid >= 128 && tid < 160) msh[tid - 128] = merge_w[tid - 128];
    __syncthreads();
    {
        const int d = tid & 63, p = tid >> 6;
        float sv = 0.f;
        #pragma unroll
        for (int i = 0; i < 16; i++) {
            int e = p * 16 + i;
            sv = fmaf(v_w[d * DM + e], em_s[e], sv);
        }
        sh[tid] = sv;
    }
    __syncthreads();
    if (tid < DM) vv[tid] = (sh[tid] + sh[64 + tid]) + (sh[128 + tid] + sh[192 + tid]);
    __syncthreads();
    {
        const int o = tid & 63, hh0 = tid >> 6;
        float s = 0.f;
        #pragma unroll
        for (int i = 0; i < DH; i++)
            s = fmaf(o_w[o * DM + hh0 * DH + i], vv[hh0 * DH + i], s);
        ov_s[o * NH + hh0] = s;
    }

    const int sl = tid & 15, h = (tid >> 4) & 3, cg_ = tid >> 6;
    float acc = 0.f;
    #pragma unroll
    for (int k = 0; k < 8; k++) {
        const int c = cg_ * 8 + k;
        const int n = b * CH + c;
        const float ts = x[(b * S_ + s0 + sl) * CH + c];
        const float u0 = (ts - hdr_s[c][0]) * hdr_s[c][1];
        const float u  = fminf(fmaxf(u0, 0.f), (float)(NNODE - 1));
        int i = (int)u;
        i = i > (NNODE - 2) ? (NNODE - 2) : i;
        const float f = u - (float)i;
        const float* T = ws + WS_T + (n * NH + h) * NNODE;
        const float t0 = T[i], t1 = T[i + 1];
        const float w = fmaf(f, t1 - t0, t0);
        acc = fmaf(msh[c], w, acc);
    }
    part[cg_][h][sl] = acc;
    __syncthreads();   // ov_s and part complete
    if (tid < 64) {
        int hh = tid >> 4, ss = tid & 15;
        W2[hh][ss] = (part[0][hh][ss] + part[1][hh][ss]) +
                     (part[2][hh][ss] + part[3][hh][ss]);
    }
    __syncthreads();
    #pragma unroll
    for (int rep = 0; rep < 4; rep++) {
        int idx = rep * 256 + tid;
        int o2 = idx & 63, ss = idx >> 6;
        float r = 0.f;
        #pragma unroll
        for (int hh = 0; hh < NH; hh++)
            r = fmaf(ov_s[o2 * NH + hh], W2[hh][ss], r);
        out[(b * S_ + s0 + ss) * COUT + o2] = r;
    }
}

extern "C" void kernel_launch(void* const* d_in, const int* in_sizes, int n_in,
                              void* d_out, int out_size, void* d_ws, size_t ws_size,
                              hipStream_t stream) {
    const float* x       = (const float*)d_in[0];
    const float* embed_w = (const float*)d_in[1];
    const float* q_w     = (const float*)d_in[2];
    const float* k_w     = (const float*)d_in[3];
    const float* v_w     = (const float*)d_in[4];
    const float* o_w     = (const float*)d_in[5];
    const float* merge_w = (const float*)d_in[6];
    float* ws  = (float*)d_ws;
    float* out = (float*)d_out;

    k_tab<<<256, 256, 0, stream>>>(x, embed_w, q_w, k_w, ws);
    k_fin<<<B_ * 64, 256, 0, stream>>>(ws, x, embed_w, v_w, o_w, merge_w, out);
}